// Round 25
// baseline (35.463 us; speedup 1.0000x reference)
//
#include <hip/hip_runtime.h>

// ConvDatapath: bit-serial crossbar conv with per-chunk ADC quantization.
// R24 state: k_q v4 15.3 + k_d 18.8. This round:
// k_q v6: x-rows stored DIRECTLY to global in padded row-major (col =
//         k + 12*(k/116), stride 656) — coalesced byte stores (v3-proven
//         12.4us), no LDS bounce/scatter. w-rows (blocks 1568..1599,
//         block-uniform branch) keep v4 LDS->fragment-Wq path.
// k_d v5: R24 is-split; X-tile = contiguous 10,496B row-major block staged
//         into LDS (coalesced b128), fragments read at i16*656+g*16+ch*128
//         (R21/R22-proven, 2-way banks = free). W: direct global fragments.
// Integer path bit-exact vs reference. Nx=6272, Ny=128, K=576 (5x116->128).

#define NXROW 6272
#define KDIM  576
#define NPB   116
#define SSTR  656    // row stride: 41*16, b128-aligned; 164 dw % 32 = 4

typedef int i32x4 __attribute__((ext_vector_type(4)));

__device__ __forceinline__ i32x4 slice2b(i32x4 v, int sh) {
    i32x4 r;
    r[0] = (int)(((unsigned)v[0] >> sh) & 0x03030303u);
    r[1] = (int)(((unsigned)v[1] >> sh) & 0x03030303u);
    r[2] = (int)(((unsigned)v[2] >> sh) & 0x03030303u);
    r[3] = (int)(((unsigned)v[3] >> sh) & 0x03030303u);
    return r;
}

// ---------------- kernel 1: quantization, one row per wave ----------------
// wave W < 6272: x-row -> padded row-major global (coalesced byte stores).
// wave W >= 6272: w-row -> LDS bounce -> fragment-layout Wq (R21 v4 path).
__global__ __launch_bounds__(256) void k_q(
    const float* __restrict__ x, const float* __restrict__ w,
    unsigned char* __restrict__ Xq, unsigned char* __restrict__ Wq,
    float* __restrict__ xsc, float* __restrict__ xof, float* __restrict__ xsm,
    float* __restrict__ wsc, float* __restrict__ wof, float* __restrict__ wsm)
{
    __shared__ __align__(16) unsigned char scr[4][SSTR];  // w-path only

    int tid = threadIdx.x, wv = tid >> 6, lane = tid & 63;
    int W = blockIdx.x * 4 + wv;          // 0..6399; branch uniform per block
    unsigned char* myrow = scr[wv];

    if (W < NXROW) {
        // ---- x path: direct padded row-major global stores
        unsigned char* rowp = Xq + (size_t)W * SSTR;
        if (lane < 16) {
            int col = lane < 12 ? (lane / 3) * 128 + 116 + (lane % 3) * 4
                                : 624 + (lane - 12) * 4;
            *(unsigned int*)(rowp + col) = 0u;
        }
        int b = W >= 3136 ? 1 : 0;
        int pos = W - b * 3136;
        int hg = pos / 56, wg = pos - hg * 56;
        const float* xb = x + (size_t)(b * 64) * 3136;
        float v[9];
#pragma unroll
        for (int r = 0; r < 9; r++) {
            int k = r * 64 + lane;
            int cin = k / 9;              // magic-mul
            int off = k - cin * 9;        // [cin][kh][kw] (ref im2col order)
            int kh = off / 3;
            int kw = off - kh * 3;
            int hr = hg - 1 + kh, wc = wg - 1 + kw;
            bool ok = ((unsigned)hr < 56u) && ((unsigned)wc < 56u);
            v[r] = ok ? xb[cin * 3136 + hr * 56 + wc] : 0.f;
        }
        float mn = v[0], mx = v[0], s = 0.f;
#pragma unroll
        for (int r = 0; r < 9; r++) { mn = fminf(mn, v[r]); mx = fmaxf(mx, v[r]); s += v[r]; }
#pragma unroll
        for (int off2 = 1; off2 < 64; off2 <<= 1) {
            mn = fminf(mn, __shfl_xor(mn, off2));
            mx = fmaxf(mx, __shfl_xor(mx, off2));
            s += __shfl_xor(s, off2);
        }
        float step = (mx - mn) / 255.0f;  // IEEE — bit-exact vs reference
        if (lane == 0) { xsc[W] = step; xof[W] = mn; xsm[W] = s; }
#pragma unroll
        for (int r = 0; r < 9; r++) {
            int q = (int)rintf((v[r] - mn) / step);   // IEEE div — bit-exact
            q = q < 0 ? 0 : (q > 255 ? 255 : q);
            int k = r * 64 + lane;
            int ch = k / NPB;
            rowp[k + 12 * ch] = (unsigned char)q;     // 64-contig byte stores
        }
    } else {
        // ---- w path: v4 LDS bounce -> fragment scatter (128 rows total)
        int row = W - NXROW;              // 0..127
        if (lane < 16) {
            int col = lane < 12 ? (lane / 3) * 128 + 116 + (lane % 3) * 4
                                : 624 + (lane - 12) * 4;
            *(unsigned int*)(myrow + col) = 0u;
        }
        const float* wr = w + (size_t)row * KDIM;
        float v[9];
#pragma unroll
        for (int r = 0; r < 9; r++) v[r] = wr[r * 64 + lane];
        float mn = v[0], mx = v[0], s = 0.f;
#pragma unroll
        for (int r = 0; r < 9; r++) { mn = fminf(mn, v[r]); mx = fmaxf(mx, v[r]); s += v[r]; }
#pragma unroll
        for (int off2 = 1; off2 < 64; off2 <<= 1) {
            mn = fminf(mn, __shfl_xor(mn, off2));
            mx = fmaxf(mx, __shfl_xor(mx, off2));
            s += __shfl_xor(s, off2);
        }
        float step = (mx - mn) / 255.0f;
        if (lane == 0) { wsc[row] = step; wof[row] = mn; wsm[row] = s; }
#pragma unroll
        for (int r = 0; r < 9; r++) {
            int q = (int)rintf((v[r] - mn) / step);
            q = q < 0 ? 0 : (q > 255 ? 255 : q);
            int k = r * 64 + lane;
            int ch = k / NPB;
            myrow[k + 12 * ch] = (unsigned char)q;
        }
        __syncthreads();   // uniform within block (all 4 waves are w-path)
        if (lane < 40) {
            int u = lane;
            i32x4 seg = *(const i32x4*)(myrow + u * 16);
            int dst16 = (u >> 3) * 128 + ((u >> 2) & 1) * 64 + (u & 3) * 16 + (row & 15);
            *(i32x4*)(Wq + (size_t)(row >> 4) * 10240 + (size_t)dst16 * 16) = seg;
        }
    }
}

// ---------------- kernel 2: crossbar MFMA + ADC + dequant (is-split) --------
// block = output tile; wave = input-slice; X staged row-major -> LDS.
__global__ __launch_bounds__(256) void k_d(
    const unsigned char* __restrict__ Xq, const unsigned char* __restrict__ Wq,
    const float* __restrict__ xscg, const float* __restrict__ xofg,
    const float* __restrict__ xsmg,
    const float* __restrict__ wscg, const float* __restrict__ wofg,
    const float* __restrict__ wsmg, float* __restrict__ out)
{
    __shared__ __align__(16) unsigned char xlds[16 * SSTR];   // 10,496 B
    __shared__ __align__(16) int pacc[4][64][4];

    int tid = threadIdx.x, wv = tid >> 6, lane = tid & 63;
    int g = lane >> 4, i16 = lane & 15;
    int blk = blockIdx.x;                 // 0..3135
    int ct = blk & 7, rtile = blk >> 3;
    const unsigned char* xt = Xq + (size_t)rtile * (16 * SSTR);
    const unsigned char* wt = Wq + (size_t)ct * 10240 + lane * 16;

    // stage the contiguous row-major X tile (16 rows x 656 B), coalesced
    for (int idx = tid; idx < 16 * SSTR / 16; idx += 256)
        *(i32x4*)(xlds + (size_t)idx * 16) = *(const i32x4*)(xt + (size_t)idx * 16);
    __syncthreads();

    const unsigned char* xp = xlds + i16 * SSTR + g * 16;   // R21/R22-proven
    int ish = 6 - 2 * wv;                 // wave-uniform input-slice shift
    const i32x4 zero = {0, 0, 0, 0};
    i32x4 acc4[4] = {{0,0,0,0},{0,0,0,0},{0,0,0,0},{0,0,0,0}};

#pragma unroll
    for (int ch = 0; ch < 5; ch++) {
        i32x4 x0 = *(const i32x4*)(xp + ch * 128);
        i32x4 x1 = *(const i32x4*)(xp + ch * 128 + 64);
        i32x4 w0 = *(const i32x4*)(wt + ch * 2048);
        i32x4 w1 = *(const i32x4*)(wt + ch * 2048 + 1024);
        i32x4 a0 = slice2b(x0, ish), a1 = slice2b(x1, ish);
#pragma unroll
        for (int ws = 0; ws < 4; ws++) {
            i32x4 b0 = slice2b(w0, 6 - 2 * ws);
            i32x4 b1 = slice2b(w1, 6 - 2 * ws);
            i32x4 d = __builtin_amdgcn_mfma_i32_16x16x64_i8(b0, a0, zero, 0, 0, 0);
            d = __builtin_amdgcn_mfma_i32_16x16x64_i8(b1, a1, d, 0, 0, 0);
            int sh = ish + 6 - 2 * ws;
#pragma unroll
            for (int r = 0; r < 4; r++) {
                int z = d[r];
                z = z > 1024 ? 1024 : z;                 // ADC clip (z >= 0)
                int t = (z >> 2) & 1;
                int r4 = (z + 1 + t) & ~3;               // round-half-even, mult of 4
                acc4[ws][r] += r4 << sh;                 // 2^(ish+wsh)
            }
        }
    }

    i32x4 acc;
#pragma unroll
    for (int r = 0; r < 4; r++)
        acc[r] = (acc4[0][r] + acc4[1][r]) + (acc4[2][r] + acc4[3][r]);  // exact

    if (wv != 0) *(i32x4*)&pacc[wv][lane][0] = acc;
    __syncthreads();

    if (wv == 0) {
        i32x4 p1 = *(const i32x4*)&pacc[1][lane][0];
        i32x4 p2 = *(const i32x4*)&pacc[2][lane][0];
        i32x4 p3 = *(const i32x4*)&pacc[3][lane][0];
#pragma unroll
        for (int r = 0; r < 4; r++)
            acc[r] = (acc[r] + p1[r]) + (p2[r] + p3[r]);   // is-sum, exact

        // epilogue: D[row = w-row (g*4+r), col = x-row (i16)]; 64B coalesced
        int b = rtile >= 196 ? 1 : 0;
        int xrow = rtile * 16 + i16;
        float xs_ = xscg[xrow], xo = xofg[xrow], xsv = xsmg[xrow];
        int hw = (rtile - 196 * b) * 16 + i16;
#pragma unroll
        for (int r = 0; r < 4; r++) {
            int wrow = ct * 16 + g * 4 + r;
            float tt = ((float)acc[r] * xs_) * wscg[wrow];
            float res = ((tt + xo * wsmg[wrow]) + wofg[wrow] * xsv)
                      - (xo * wofg[wrow]) * 576.0f;
            out[(size_t)(b * 128 + wrow) * 3136 + hw] = res;
        }
    }
}

extern "C" void kernel_launch(void* const* d_in, const int* in_sizes, int n_in,
                              void* d_out, int out_size, void* d_ws, size_t ws_size,
                              hipStream_t stream) {
    const float* x = (const float*)d_in[0];   // [2][64][56][56]
    const float* w = (const float*)d_in[1];   // [128][64][3][3]
    float* out = (float*)d_out;               // [2][128][56][56]

    unsigned char* Xq = (unsigned char*)d_ws;          // 6272*656 = 4,114,432 B
    unsigned char* Wq = Xq + (size_t)NXROW * SSTR;     // 8*10,240 = 81,920 B
    float* xsc = (float*)(Wq + 8 * 10240);
    float* xof = xsc + NXROW;
    float* xsm = xof + NXROW;
    float* wsc = xsm + NXROW;
    float* wof = wsc + 128;
    float* wsm = wof + 128;

    hipLaunchKernelGGL(k_q, dim3(1600), dim3(256), 0, stream,
                       x, w, Xq, Wq, xsc, xof, xsm, wsc, wof, wsm);
    hipLaunchKernelGGL(k_d, dim3(3136), dim3(256), 0, stream,
                       Xq, Wq, xsc, xof, xsm, wsc, wof, wsm, out);
}

// Round 26
// 33.544 us; speedup vs baseline: 1.0572x; 1.0572x over previous
//
#include <hip/hip_runtime.h>

// ConvDatapath: bit-serial crossbar conv with per-chunk ADC quantization.
// R21 anchor 33.9 = k_q v4 15.3 + k_d R11 18.6. One change this round:
// k_q v7: per-wave LDS row bounce (v4-proven) + BLOCK-COOPERATIVE fragment
//         store — a block's 4 rows share one tile, so (u, rl..rl+3) segments
//         form contiguous 64B lines: tid<160, 4 tids per line (4x fewer
//         store transactions than v4's per-wave 40-line scatter).
// k_d   : R11 verbatim (18.6us measured; best across all variants).
// Integer path bit-exact vs reference. Nx=6272, Ny=128, K=576 (5x116->128).

#define NXROW 6272
#define KDIM  576
#define NPB   116
#define SSTR  656    // LDS row stride: 41*16, b128-aligned; 164 dw % 32 = 4

typedef int i32x4 __attribute__((ext_vector_type(4)));

__device__ __forceinline__ i32x4 slice2b(i32x4 v, int sh) {
    i32x4 r;
    r[0] = (int)(((unsigned)v[0] >> sh) & 0x03030303u);
    r[1] = (int)(((unsigned)v[1] >> sh) & 0x03030303u);
    r[2] = (int)(((unsigned)v[2] >> sh) & 0x03030303u);
    r[3] = (int)(((unsigned)v[3] >> sh) & 0x03030303u);
    return r;
}

// ---------------- kernel 1: quantization, one row per wave ----------------
// wave W < 6272: im2col x-row W; else w-row W-6272. Rows 4b..4b+3 share one
// 16-row tile (never cross a 16-boundary) and one side (6272 % 4 == 0).
__global__ __launch_bounds__(256) void k_q(
    const float* __restrict__ x, const float* __restrict__ w,
    unsigned char* __restrict__ Xq, unsigned char* __restrict__ Wq,
    float* __restrict__ xsc, float* __restrict__ xof, float* __restrict__ xsm,
    float* __restrict__ wsc, float* __restrict__ wof, float* __restrict__ wsm)
{
    __shared__ __align__(16) unsigned char scr[4][SSTR];  // per-wave row

    int tid = threadIdx.x, wv = tid >> 6, lane = tid & 63;
    int W = blockIdx.x * 4 + wv;          // 0..6399, wave-uniform
    unsigned char* myrow = scr[wv];

    // zero this row's K-pad dwords (cols ch*128+116..127, 624..639)
    if (lane < 16) {
        int col = lane < 12 ? (lane / 3) * 128 + 116 + (lane % 3) * 4
                            : 624 + (lane - 12) * 4;
        *(unsigned int*)(myrow + col) = 0u;
    }

    float v[9];
    float *sc, *of, *sm;
    int sidx;

    if (W < NXROW) {
        int b = W >= 3136 ? 1 : 0;
        int pos = W - b * 3136;
        int hg = pos / 56, wg = pos - hg * 56;
        const float* xb = x + (size_t)(b * 64) * 3136;
#pragma unroll
        for (int r = 0; r < 9; r++) {
            int k = r * 64 + lane;
            int cin = k / 9;              // magic-mul
            int off = k - cin * 9;        // [cin][kh][kw] (ref im2col order)
            int kh = off / 3;
            int kw = off - kh * 3;
            int hr = hg - 1 + kh, wc = wg - 1 + kw;
            bool ok = ((unsigned)hr < 56u) && ((unsigned)wc < 56u);
            v[r] = ok ? xb[cin * 3136 + hr * 56 + wc] : 0.f;
        }
        sc = xsc; of = xof; sm = xsm; sidx = W;
    } else {
        int row = W - NXROW;              // 0..127
        const float* wr = w + (size_t)row * KDIM;
#pragma unroll
        for (int r = 0; r < 9; r++) v[r] = wr[r * 64 + lane];
        sc = wsc; of = wof; sm = wsm; sidx = row;
    }

    // stats: exact min/max; butterfly sum (R20/R21-proven, absmax 0.75)
    float mn = v[0], mx = v[0], s = 0.f;
#pragma unroll
    for (int r = 0; r < 9; r++) { mn = fminf(mn, v[r]); mx = fmaxf(mx, v[r]); s += v[r]; }
#pragma unroll
    for (int off2 = 1; off2 < 64; off2 <<= 1) {
        mn = fminf(mn, __shfl_xor(mn, off2));
        mx = fmaxf(mx, __shfl_xor(mx, off2));
        s += __shfl_xor(s, off2);
    }
    float step = (mx - mn) / 255.0f;      // IEEE — bit-exact vs reference
    if (lane == 0) { sc[sidx] = step; of[sidx] = mn; sm[sidx] = s; }

    // quantize into this wave's LDS row: col = k + 12*(k/116) = ch*128 + k%116
#pragma unroll
    for (int r = 0; r < 9; r++) {
        int q = (int)rintf((v[r] - mn) / step);   // IEEE div — bit-exact
        q = q < 0 ? 0 : (q > 255 ? 255 : q);
        int k = r * 64 + lane;
        int ch = k / NPB;
        myrow[k + 12 * ch] = (unsigned char)q;
    }
    __syncthreads();   // uniform: orders LDS writes before cooperative store

    // block-cooperative fragment store: 160 segments (4 rows x 40 u).
    // dst16 = (u>>3)*128 + ((u>>2)&1)*64 + (u&3)*16 + rl; 4 consecutive tids
    // (same u, dr=0..3) write 4 consecutive 16B runs = one 64B line.
    if (tid < 160) {
        int u = tid >> 2, dr = tid & 3;
        int row0 = blockIdx.x * 4;        // block-uniform
        bool isx = row0 < NXROW;
        int lrow = (isx ? row0 : row0 - NXROW) + dr;
        int tile = lrow >> 4, rl = lrow & 15;
        unsigned char* dstbase = (isx ? Xq : Wq) + (size_t)tile * 10240;
        i32x4 seg = *(const i32x4*)(scr[dr] + u * 16);
        int dst16 = (u >> 3) * 128 + ((u >> 2) & 1) * 64 + (u & 3) * 16 + rl;
        *(i32x4*)(dstbase + (size_t)dst16 * 16) = seg;
    }
}

// ---------------- kernel 2: crossbar MFMA + ADC + dequant (R11 verbatim) ----
// one chunk, accumulating into 4 per-ws accumulators (4 indep chains)
__device__ __forceinline__ void chunk_ws(const unsigned char* xt, const unsigned char* wt,
                                         int ch, int lane, i32x4 (&acc4)[4])
{
    const i32x4 zero = {0, 0, 0, 0};
    i32x4 x0 = *(const i32x4*)(xt + ch * 2048 + lane * 16);
    i32x4 x1 = *(const i32x4*)(xt + ch * 2048 + 1024 + lane * 16);
    i32x4 w0 = *(const i32x4*)(wt + ch * 2048 + lane * 16);
    i32x4 w1 = *(const i32x4*)(wt + ch * 2048 + 1024 + lane * 16);
    i32x4 ws0[4], ws1[4];
#pragma unroll
    for (int ws = 0; ws < 4; ws++) {
        ws0[ws] = slice2b(w0, 6 - 2 * ws);
        ws1[ws] = slice2b(w1, 6 - 2 * ws);
    }
#pragma unroll
    for (int is = 0; is < 4; is++) {
        int ish = 6 - 2 * is;
        i32x4 a0 = slice2b(x0, ish), a1 = slice2b(x1, ish);
#pragma unroll
        for (int ws = 0; ws < 4; ws++) {
            i32x4 d = __builtin_amdgcn_mfma_i32_16x16x64_i8(ws0[ws], a0, zero, 0, 0, 0);
            d = __builtin_amdgcn_mfma_i32_16x16x64_i8(ws1[ws], a1, d, 0, 0, 0);
            int sh = ish + 6 - 2 * ws;
#pragma unroll
            for (int r = 0; r < 4; r++) {
                int z = d[r];
                z = z > 1024 ? 1024 : z;                 // ADC clip (z >= 0)
                int t = (z >> 2) & 1;
                int r4 = (z + 1 + t) & ~3;               // round-half-even, mult of 4
                acc4[ws][r] += r4 << sh;                 // 2^(ish+wsh)
            }
        }
    }
}

__global__ __launch_bounds__(256) void k_d(
    const unsigned char* __restrict__ Xq, const unsigned char* __restrict__ Wq,
    const float* __restrict__ xscg, const float* __restrict__ xofg,
    const float* __restrict__ xsmg,
    const float* __restrict__ wscg, const float* __restrict__ wofg,
    const float* __restrict__ wsmg, float* __restrict__ out)
{
    __shared__ __align__(16) int pacc[2][64][4];

    int tid = threadIdx.x, wv = tid >> 6, lane = tid & 63;
    int g = lane >> 4, i16 = lane & 15;
    int blk = blockIdx.x;                 // 0..1567
    int ct = blk & 7, rp = blk >> 3;      // rp 0..195
    int tl = wv & 1, khalf = wv >> 1;
    int rtile = rp * 2 + tl;              // 0..391
    const unsigned char* xt = Xq + (size_t)rtile * 10240;
    const unsigned char* wt = Wq + (size_t)ct * 10240;

    i32x4 acc4[4] = {{0,0,0,0},{0,0,0,0},{0,0,0,0},{0,0,0,0}};
    if (khalf == 0) {
        chunk_ws(xt, wt, 0, lane, acc4);
        chunk_ws(xt, wt, 1, lane, acc4);
        chunk_ws(xt, wt, 2, lane, acc4);
    } else {
        chunk_ws(xt, wt, 3, lane, acc4);
        chunk_ws(xt, wt, 4, lane, acc4);
    }
    i32x4 acc;
#pragma unroll
    for (int r = 0; r < 4; r++)
        acc[r] = (acc4[0][r] + acc4[1][r]) + (acc4[2][r] + acc4[3][r]);  // exact

    if (khalf == 0) *(i32x4*)&pacc[tl][lane][0] = acc;
    __syncthreads();

    if (khalf == 1) {
        i32x4 p = *(const i32x4*)&pacc[tl][lane][0];
#pragma unroll
        for (int r = 0; r < 4; r++) acc[r] += p[r];      // chunk-sum, exact

        // epilogue: D[row = w-row (g*4+r), col = x-row (i16)]; 64B coalesced
        int b = rtile >= 196 ? 1 : 0;
        int xrow = rtile * 16 + i16;
        float xs_ = xscg[xrow], xo = xofg[xrow], xsv = xsmg[xrow];
        int hw = (rtile - 196 * b) * 16 + i16;
#pragma unroll
        for (int r = 0; r < 4; r++) {
            int wrow = ct * 16 + g * 4 + r;
            float tt = ((float)acc[r] * xs_) * wscg[wrow];
            float res = ((tt + xo * wsmg[wrow]) + wofg[wrow] * xsv)
                      - (xo * wofg[wrow]) * 576.0f;
            out[(size_t)(b * 128 + wrow) * 3136 + hw] = res;
        }
    }
}

extern "C" void kernel_launch(void* const* d_in, const int* in_sizes, int n_in,
                              void* d_out, int out_size, void* d_ws, size_t ws_size,
                              hipStream_t stream) {
    const float* x = (const float*)d_in[0];   // [2][64][56][56]
    const float* w = (const float*)d_in[1];   // [128][64][3][3]
    float* out = (float*)d_out;               // [2][128][56][56]

    unsigned char* Xq = (unsigned char*)d_ws;          // 392*10,240 = 4,014,080 B
    unsigned char* Wq = Xq + (size_t)392 * 10240;      // 8*10,240   = 81,920 B
    float* xsc = (float*)(Wq + 8 * 10240);
    float* xof = xsc + NXROW;
    float* xsm = xof + NXROW;
    float* wsc = xsm + NXROW;
    float* wof = wsc + 128;
    float* wsm = wof + 128;

    hipLaunchKernelGGL(k_q, dim3(1600), dim3(256), 0, stream,
                       x, w, Xq, Wq, xsc, xof, xsm, wsc, wof, wsm);
    hipLaunchKernelGGL(k_d, dim3(1568), dim3(256), 0, stream,
                       Xq, Wq, xsc, xof, xsm, wsc, wof, wsm, out);
}